// Round 11
// baseline (96.003 us; speedup 1.0000x reference)
//
#include <hip/hip_runtime.h>

#define NB 8
#define NN 1024
#define NH 32

// ---- warped-grid me(s,t) table ----
// u = s/(1+|s|/C) maps s in [-R,R] to u in [-U,U], U = C*R/(C+R).
#define FP 99              // grid points per axis; cells (FP-1)^2
#define CW 6.0f            // warp constant C
#define RW 7.5f            // range covered exactly
#define UW (CW * RW / (CW + RW))   // 10/3

__device__ __forceinline__ float leaky(float x) { return fmaxf(x, 0.01f * x); }

__device__ __forceinline__ float fast_tanh(float x) {
    float e = __builtin_amdgcn_exp2f(x * 2.88539008177792681f);
    return 1.0f - 2.0f * __builtin_amdgcn_rcpf(1.0f + e);
}

#define SWZ_ADD(v, imm) \
    v += __int_as_float(__builtin_amdgcn_ds_swizzle(__float_as_int(v), imm))

__device__ __forceinline__ unsigned bf16r(float f) {   // fp32 -> bf16 bits, RNE
    unsigned u = __float_as_uint(f);
    return (u + 0x7FFFu + ((u >> 16) & 1u)) >> 16;
}

// ---------------- eval: transposed — lane&31 = hidden channel h ----------------
// One wave evaluates TWO grid points (lane>>5 = which). Per k: h1k computed
// per-lane from wave-uniform Wm1/bm1 (K$ scalar loads); Wm2[k*32+h] is one
// coalesced 128B vector load (L1-hot). Butterfly-reduce over the 32-lane half.
__global__ __launch_bounds__(256) void eval_kernel(
    const float* __restrict__ Wm1, const float* __restrict__ bm1,
    const float* __restrict__ Wm2, const float* __restrict__ bm2,
    const float* __restrict__ Wm3, const float* __restrict__ bm3,
    float* __restrict__ tabf) {
    const int tid  = threadIdx.x;
    const int wav  = blockIdx.x * 4 + (tid >> 6);
    const int lane = tid & 63;
    const int half = lane >> 5;
    const int h    = lane & 31;
    const int p    = wav * 2 + half;               // grid-point id
    const bool valid = p < FP * FP;
    const int pp = valid ? p : 0;
    const int iy = pp / FP;
    const int ix = pp - iy * FP;

    const float hu = 2.0f * UW / (float)(FP - 1);
    const float us = fmaf((float)ix, hu, -UW);
    const float ut = fmaf((float)iy, hu, -UW);
    const float s = us / (1.0f - fabsf(us) / CW);  // unwarp (exact div)
    const float t = ut / (1.0f - fabsf(ut) / CW);

    float acc = bm2[h];
#pragma unroll
    for (int k = 0; k < NH; ++k) {
        const float h1k = leaky(s * Wm1[k] + t * Wm1[32 + k] + bm1[k]);
        acc = fmaf(h1k, Wm2[k * 32 + h], acc);
    }
    float v = leaky(acc) * Wm3[h];
    SWZ_ADD(v, 0x041F);   // xor 1   (within 32-lane group)
    SWZ_ADD(v, 0x081F);   // xor 2
    SWZ_ADD(v, 0x101F);   // xor 4
    SWZ_ADD(v, 0x201F);   // xor 8
    SWZ_ADD(v, 0x401F);   // xor 16
    if (valid && h == 0) tabf[p] = fast_tanh(v + bm3[0]);
}

// ---------------- assemble packed cells (ONE pass, not per edge-block) ----
// cell = { fp32 f00, bf16(f10-f00) | bf16(f01-f00)<<16 }
__global__ __launch_bounds__(256) void assemble_kernel(
    const float* __restrict__ tabf, uint2* __restrict__ tq) {
    const int gid = blockIdx.x * 256 + threadIdx.x;
    if (gid >= FP * FP) return;
    const int iy = gid / FP;
    const int ix = gid - iy * FP;
    if (ix >= FP - 1 || iy >= FP - 1) { tq[gid] = make_uint2(0u, 0u); return; }
    const float f00 = tabf[gid];
    const float f10 = tabf[gid + 1];
    const float f01 = tabf[gid + FP];
    uint2 cell;
    cell.x = __float_as_uint(f00);
    cell.y = bf16r(f10 - f00) | (bf16r(f01 - f00) << 16);
    tq[gid] = cell;
}

// ---------------- edge lookup + row sum + fused output MLP ----------------
// 1024 threads = 16 waves; wave owns one (b,i); 2 blocks/CU (78 KB LDS, 64 VGPR).
// Staging is a plain dwordx4 copy of pre-assembled cells (no per-block repack).
__global__ __launch_bounds__(1024, 8) void edge_out_kernel(
    const float* __restrict__ x, const float* __restrict__ A,
    const uint2* __restrict__ tq,
    const float* __restrict__ Wx1, const float* __restrict__ bx1,
    const float* __restrict__ Wx2, const float* __restrict__ bx2,
    const float* __restrict__ Wx3, const float* __restrict__ bx3,
    float* __restrict__ out) {
    __shared__ uint2 sfq[FP * FP];                     // 78,408 B

    const int tid = threadIdx.x;
    {
        const float4* __restrict__ src = (const float4*)tq;
        float4* dst = (float4*)sfq;
        for (int idx = tid; idx < (FP * FP) / 2; idx += 1024) dst[idx] = src[idx];
        if (tid == 0) sfq[FP * FP - 1] = tq[FP * FP - 1];
    }
    __syncthreads();

    const int wave = tid >> 6;
    const int lane = tid & 63;
    const int w    = blockIdx.x * 16 + wave;           // < 8192
    const int i    = w >> 3;
    const int b    = w & 7;
    const int node = b * NN + i;

    const float2 xi = ((const float2*)x)[node];        // wave-uniform
    const float4* __restrict__ xb4 = (const float4*)((const float2*)x + b * NN);
    const float2* __restrict__ Ar2 = (const float2*)(A + (size_t)i * NN);

    const float hu     = 2.0f * UW / (float)(FP - 1);
    const float inv_hu = 1.0f / hu;
    const float fhi    = (float)(FP - 1) - 0.001f;
    const float rcw    = 1.0f / CW;

    float ms0 = 0.0f, ms1 = 0.0f, ms2 = 0.0f, ms3 = 0.0f;
#pragma unroll
    for (int g = 0; g < 2; ++g) {
        float4 xv[4]; float2 av[4];
#pragma unroll
        for (int q = 0; q < 4; ++q) {
            const int p = (g * 4 + q) * 64 + lane;     // pair index
            xv[q] = xb4[p];                            // nodes 2p, 2p+1
            av[q] = Ar2[p];
        }
        int   idxq[8];
        float asq[8], atq[8];
#pragma unroll
        for (int q = 0; q < 4; ++q) {
#pragma unroll
            for (int e = 0; e < 2; ++e) {
                const float s = xi.x + (e ? xv[q].z : xv[q].x);
                const float t = xi.y + (e ? xv[q].w : xv[q].y);
                const float us = s * __builtin_amdgcn_rcpf(fmaf(fabsf(s), rcw, 1.0f));
                const float ut = t * __builtin_amdgcn_rcpf(fmaf(fabsf(t), rcw, 1.0f));
                const float fs = fminf(fmaxf((us + UW) * inv_hu, 0.0f), fhi);
                const float ft = fminf(fmaxf((ut + UW) * inv_hu, 0.0f), fhi);
                const float fsf = floorf(fs), ftf = floorf(ft);
                asq[q * 2 + e] = fs - fsf;
                atq[q * 2 + e] = ft - ftf;
                idxq[q * 2 + e] = (int)ftf * FP + (int)fsf;
            }
        }
        uint2 cqv[8];
#pragma unroll
        for (int q = 0; q < 8; ++q) cqv[q] = sfq[idxq[q]];
#pragma unroll
        for (int q = 0; q < 8; ++q) {
            const float c00 = __uint_as_float(cqv[q].x);
            const float dcs = __uint_as_float(cqv[q].y << 16);
            const float dct = __uint_as_float(cqv[q].y & 0xFFFF0000u);
            const float me  = fmaf(atq[q], dct, fmaf(asq[q], dcs, c00));
            const float aw  = (q & 1) ? av[q >> 1].y : av[q >> 1].x;
            if      ((q & 3) == 0) ms0 = fmaf(me, aw, ms0);
            else if ((q & 3) == 1) ms1 = fmaf(me, aw, ms1);
            else if ((q & 3) == 2) ms2 = fmaf(me, aw, ms2);
            else                   ms3 = fmaf(me, aw, ms3);
        }
    }
    float msum = (ms0 + ms1) + (ms2 + ms3);

    // full-wave butterfly: every lane ends with the row sum
    SWZ_ADD(msum, 0x041F);
    SWZ_ADD(msum, 0x081F);
    SWZ_ADD(msum, 0x101F);
    SWZ_ADD(msum, 0x201F);
    SWZ_ADD(msum, 0x401F);
    msum += __shfl_xor(msum, 32, 64);

    // ---- fused output MLP (transient-k, no h1x array) ----
    const float rho = xi.x;
    const int h = lane & 31;
    float acc = bx2[h];
#pragma unroll
    for (int k = 0; k < NH; ++k) {
        const float h1k = leaky(fmaf(msum, Wx1[32 + k], fmaf(rho, Wx1[k], bx1[k])));
        acc = fmaf(h1k, Wx2[k * 32 + h], acc);
    }
    float sv = (lane < 32) ? leaky(acc) * Wx3[h] : 0.0f;
    SWZ_ADD(sv, 0x041F);
    SWZ_ADD(sv, 0x081F);
    SWZ_ADD(sv, 0x101F);
    SWZ_ADD(sv, 0x201F);
    SWZ_ADD(sv, 0x401F);
    sv += __shfl_xor(sv, 32, 64);
    if (lane == 0) out[node] = fast_tanh(sv + bx3[0]);
}

extern "C" void kernel_launch(void* const* d_in, const int* in_sizes, int n_in,
                              void* d_out, int out_size, void* d_ws, size_t ws_size,
                              hipStream_t stream) {
    const float* x   = (const float*)d_in[0];
    const float* A   = (const float*)d_in[1];
    const float* Wm1 = (const float*)d_in[2];
    const float* bm1 = (const float*)d_in[3];
    const float* Wm2 = (const float*)d_in[4];
    const float* bm2 = (const float*)d_in[5];
    const float* Wm3 = (const float*)d_in[6];
    const float* bm3 = (const float*)d_in[7];
    const float* Wx1 = (const float*)d_in[8];
    const float* bx1 = (const float*)d_in[9];
    const float* Wx2 = (const float*)d_in[10];
    const float* bx2 = (const float*)d_in[11];
    const float* Wx3 = (const float*)d_in[12];
    const float* bx3 = (const float*)d_in[13];

    uint2* tq   = (uint2*)d_ws;                        // FP*FP packed cells (78.4 KB)
    float* tabf = (float*)(tq + FP * FP);              // FP*FP point values (39 KB)
    float* out  = (float*)d_out;

    const int npairs = (FP * FP + 1) / 2;              // waves needed
    const int nblk   = (npairs + 3) / 4;               // 4 waves per block
    eval_kernel<<<dim3(nblk), dim3(256), 0, stream>>>(
        Wm1, bm1, Wm2, bm2, Wm3, bm3, tabf);
    assemble_kernel<<<dim3((FP * FP + 255) / 256), dim3(256), 0, stream>>>(tabf, tq);
    edge_out_kernel<<<dim3(NB * NN / 16), dim3(1024), 0, stream>>>(
        x, A, tq, Wx1, bx1, Wx2, bx2, Wx3, bx3, out);
}